// Round 14
// baseline (586.288 us; speedup 1.0000x reference)
//
#include <hip/hip_runtime.h>
#include <math.h>

// ExperimentalModel_1752346656819: 4-stage dynamic-conv decoder, fp32 compute.
// R29: packed FP32 FMA. Instruction accounting (VALUBusy 58% x 250us = 145us
// matches the scalar-fma model, not the packed one) shows the compiler is
// NOT emitting v_pk_fma_f32 for v2f math. Fix: inline-asm v_pk_fma_f32 with
// VOP3P op_sel broadcasting one word of the (already-pair-loaded) tile
// operand -- zero splat movs, per-accumulator update order preserved
// (bit-exact). convt's -= handled by negating tile at staging (exact).
// convm/convt/convr inner loops only; strips stay plain C. Base = R28.

#define BLK 256
#define EF 2.7182818284590452f
#define FINF 3.4e38f

typedef float v2f __attribute__((ext_vector_type(2)));

// acc += w * broadcast(word0 of pair) / broadcast(word1 of pair)
#define PK_LO(a, w, pair) \
  asm("v_pk_fma_f32 %0, %1, %2, %0 op_sel_hi:[1,0,1]" \
      : "+v"(a) : "v"(w), "v"(pair))
#define PK_HI(a, w, pair) \
  asm("v_pk_fma_f32 %0, %1, %2, %0 op_sel:[0,1,0] op_sel_hi:[1,1,1]" \
      : "+v"(a) : "v"(w), "v"(pair))

struct W1Args { const float* M[12]; float* out[12]; };
struct W2Args { const float* W[4]; const float* u[4]; const float* v[4]; float* out[4]; };

__device__ __forceinline__ unsigned short f2b(float f){
  unsigned u = __float_as_uint(f);
  unsigned r = u + 0x7FFFu + ((u >> 16) & 1u);   // round-to-nearest-even
  return (unsigned short)(r >> 16);
}
__device__ __forceinline__ float b2f(unsigned short h){
  return __uint_as_float((unsigned)h << 16);
}
__device__ __forceinline__ v2f mkv(float a, float b){ v2f r; r.x=a; r.y=b; return r; }

__device__ __forceinline__ float dln_one(float y, float m){
  float a = fabsf(y) - m;
  float v = __logf(__logf(a + EF) + 0.01f);
  return (y > 0.0f) ? v : -v;
}

__global__ void gather_ctx_kernel(const int* __restrict__ ids,
                                  const float* __restrict__ cache,
                                  float* __restrict__ ctx){
  int e = blockIdx.x*blockDim.x + threadIdx.x;
  if (e < 64*32){
    int b = e >> 5, l = e & 31;
    ctx[e] = cache[(size_t)ids[b]*32 + l];
  }
}

__global__ void gather_x_kernel(const int* __restrict__ ids,
                                const float* __restrict__ lat,
                                float* __restrict__ X, int b0, int nb){
  int total = nb*2048;
  int e = blockIdx.x*blockDim.x + threadIdx.x;
  if (e < total){
    int bl = e >> 11;
    int r  = e & 2047;
    X[e] = lat[(size_t)ids[b0+bl]*2048 + r];
  }
}

__global__ void w1_kernel(const float* __restrict__ ctx, W1Args args){
  const int S[12] = {4,4,4,4,4,4,4,4,4,1,1,1};
  const int K[12] = {128,1152,128,2048,128,3200,8,8,8,48,128,3};
  int tid = blockIdx.x*blockDim.x + threadIdx.x;
  int nth = gridDim.x*blockDim.x;
  for (int seg = 0; seg < 12; ++seg){
    const float* M = args.M[seg];
    float* out = args.out[seg];
    int Ks = K[seg];
    int total = S[seg]*64*Ks;
    for (int e = tid; e < total; e += nth){
      int k = e % Ks;
      int b = (e / Ks) % 64;
      int s = e / (Ks*64);
      const float* Ms = M + (size_t)s*32*Ks + k;
      const float* cb = ctx + b*32;
      float acc = 0.f;
      #pragma unroll
      for (int l = 0; l < 32; ++l) acc += cb[l]*Ms[(size_t)l*Ks];
      out[e] = acc;
    }
  }
}

// Dynamic weights. Segs 0-2 TRANSPOSED to [s][b][i][p][q][o]; seg 3 [b][o][i].
__global__ void w2_kernel(W2Args args){
  const int S[4] = {4,4,4,1};
  const int O[4] = {8,8,8,3};
  const int K[4] = {72,128,200,8};
  const int KH[4] = {3,4,5,1};
  int tid = blockIdx.x*blockDim.x + threadIdx.x;
  int nth = gridDim.x*blockDim.x;
  for (int seg = 0; seg < 4; ++seg){
    int Os = O[seg], Ks = K[seg];
    int kh = KH[seg], kk = kh*kh;
    int total = S[seg]*64*Os*Ks;
    const float* Wt = args.W[seg];
    const float* u = args.u[seg];
    const float* v = args.v[seg];
    float* out = args.out[seg];
    for (int e = tid; e < total; e += nth){
      int k = e % Ks;
      int o = (e/Ks) % Os;
      int b = (e/(Ks*Os)) % 64;
      int s = e/(Ks*Os*64);
      const float* us = u + (size_t)(s*64+b)*16*Os;
      const float* vs = v + (size_t)(s*64+b)*16*Ks;
      float mod = 0.f;
      #pragma unroll
      for (int r = 0; r < 16; ++r) mod += us[r*Os+o]*vs[r*Ks+k];
      float val = Wt[(size_t)(s*Os+o)*Ks + k] * (1.0f + mod + 1e-3f);
      size_t dst;
      if (seg < 3){
        int i = k / kk, r2 = k - i*kk, p = r2 / kh, q = r2 - p*kh;
        dst = (size_t)(s*64+b)*(8*Ks) + (size_t)(((i*kh+p)*kh+q)*8 + o);
      } else {
        dst = (size_t)b*24 + o*8 + k;
      }
      out[dst] = val;
    }
  }
}

// Combined bilinear-upsample x conv5x5 weights on the quarter-res grid.
// For each (s,b,i,o): W2[py][tyT][px][txT] = sum_{p,q} A(py)[tyT][p] K[p][q] A(px)[txT][q]
// Layout: w2[(sb*2+py)*2048 + i*256 + tyT*64 + px*32 + txT*8 + o]
__global__ void w4_kernel(const float* __restrict__ wmdyn, float* __restrict__ w2o){
  int e = blockIdx.x*blockDim.x + threadIdx.x;
  if (e >= 16384) return;          // 4 stages * 64 samples * 8 i * 8 o
  int o = e & 7, i = (e >> 3) & 7, sb = e >> 6;
  const float* wk = wmdyn + (size_t)sb*1600 + i*200 + o;
  float K[5][5];
  #pragma unroll
  for (int p = 0; p < 5; ++p)
    #pragma unroll
    for (int q = 0; q < 5; ++q) K[p][q] = wk[(p*5+q)*8];
  const float Ae[4][5] = {{0.25f,0.f,0.f,0.f,0.f},
                          {0.75f,0.75f,0.25f,0.f,0.f},
                          {0.f,0.25f,0.75f,0.75f,0.25f},
                          {0.f,0.f,0.f,0.25f,0.75f}};
  const float Ao[4][5] = {{0.75f,0.25f,0.f,0.f,0.f},
                          {0.25f,0.75f,0.75f,0.25f,0.f},
                          {0.f,0.f,0.25f,0.75f,0.75f},
                          {0.f,0.f,0.f,0.f,0.25f}};
  #pragma unroll
  for (int py = 0; py < 2; ++py){
    float T[4][5];
    #pragma unroll
    for (int ty = 0; ty < 4; ++ty)
      #pragma unroll
      for (int q = 0; q < 5; ++q){
        float a = 0.f;
        #pragma unroll
        for (int p = 0; p < 5; ++p) a += (py ? Ao[ty][p] : Ae[ty][p]) * K[p][q];
        T[ty][q] = a;
      }
    #pragma unroll
    for (int ty = 0; ty < 4; ++ty)
      #pragma unroll
      for (int px = 0; px < 2; ++px)
        #pragma unroll
        for (int tx = 0; tx < 4; ++tx){
          float a = 0.f;
          #pragma unroll
          for (int q = 0; q < 5; ++q) a += T[ty][q] * (px ? Ao[tx][q] : Ae[tx][q]);
          w2o[(size_t)(sb*2+py)*2048 + i*256 + ty*64 + px*32 + tx*8 + o] = a;
        }
  }
}

__global__ void init_min_kernel(unsigned* __restrict__ mn, int n){
  int e = blockIdx.x*blockDim.x + threadIdx.x;
  if (e < n) mn[e] = 0x7F800000u;   // +inf
}

// Fused per-stage conv kernel. Grid:
// [0,gS)     convm border strips (exact 5x5, ONE px/thread, weights in LDS)
// [gS,g1)    convm (quarter-res combined 4x4, per-lane weights, pk-FMA)
// [g1,g2)    convt (4x4 T, per-lane weights, pk-FMA, tile negated at stage)
// [g2,..)    convr (3x3, per-lane weights, pk-FMA)
// Outputs D/T/M in bf16. LDS union 15.6 KB.
__attribute__((amdgpu_num_vgpr(48)))
__global__ void __launch_bounds__(BLK) conv3_fused(
    const float* __restrict__ X,
    const float* __restrict__ wr, const float* __restrict__ br,
    const float* __restrict__ wt, const float* __restrict__ bt,
    const float* __restrict__ wm, const float* __restrict__ bm,
    const float* __restrict__ w2,
    unsigned short* __restrict__ D, unsigned short* __restrict__ T,
    unsigned short* __restrict__ M,
    unsigned* __restrict__ mn, int maps, int H, int b0, int s,
    int tprR, int tprO, int gS, int g1, int g2){
  __shared__ __align__(16) float smem[3904];
  const int bid = blockIdx.x;

  if (bid < gS){
    // --- convm border strips: exact 5x5 on bilinear-up(log) with zero-pad.
    //     8 blocks/sample: side (0/1 rows, 2/3 cols) x 2 sub-blocks.
    //     ONE output px per thread: acc[4] v2f, (y,x,valid) precomputed.
    //     U strip + 1600 dyn weights in LDS. ---
    float* U  = smem;                         // 2*4*Hi <= 2048
    float* wl = smem + 2048;                  // 1600 floats
    const int bl = bid >> 3;
    const int r3 = bid & 7;
    const int side = r3 >> 1;
    const int kblk = r3 & 1;
    const int bg = b0 + bl;
    const int Hi = 2*H, Hq = H, HWq = Hq*Hq, HW = Hi*Hi;
    const float* wb = wm + (size_t)(s*64+bg)*1600;   // [i][p][q][o], o contig
    const float* bb = bm + (size_t)(s*64+bg)*8;
    const float* xb = X + (size_t)bl*8*HWq;
    const bool tb = (side < 2);
    const int off = (side & 1) ? Hi - 4 : 0;
    const int cnt = tb ? 2*Hi : 2*(Hi - 4);
    const int hsh = 31 - __clz(Hi);
    // stage weights (covered by the syncthreads after the first U build)
    #pragma unroll
    for (int k = 0; k < 7; ++k){
      int e = threadIdx.x + k*BLK;
      if (e < 1600) wl[e] = wb[e];
    }
    const int e2 = kblk*BLK + (int)threadIdx.x;
    const bool valid = e2 < cnt;
    int y, x;
    if (tb){
      int yl = (e2 >= Hi) ? 1 : 0;
      x = e2 - yl*Hi;
      y = (side == 0) ? yl : (Hi - 2 + yl);
    } else {
      int xl2 = (e2 >= Hi - 4) ? 1 : 0;
      y = 2 + e2 - xl2*(Hi - 4);
      x = (side == 2) ? xl2 : (Hi - 2 + xl2);
    }
    v2f acc[4];
    #pragma unroll
    for (int o2 = 0; o2 < 4; ++o2){
      v2f b2; b2.x = bb[2*o2]; b2.y = bb[2*o2+1];
      acc[o2] = b2;
    }
    const int elems = 8*Hi;
    #pragma unroll 1
    for (int ph = 0; ph < 4; ++ph){
      if (ph > 0) __syncthreads();
      #pragma unroll 1
      for (int e = threadIdx.x; e < elems; e += BLK){
        int c2 = (e >= 4*Hi) ? 1 : 0;
        int r = e - c2*4*Hi;
        int g, h;
        if (tb){ g = off + (r >> hsh); h = r & (Hi - 1); }
        else   { g = r >> 2;           h = off + (r & 3); }
        int jy = g >> 1;
        int ny = (g & 1) ? ((jy+1 < Hq) ? jy+1 : Hq-1) : ((jy > 0) ? jy-1 : 0);
        int jx = h >> 1;
        int nx = (h & 1) ? ((jx+1 < Hq) ? jx+1 : Hq-1) : ((jx > 0) ? jx-1 : 0);
        const float* lb = xb + (size_t)(2*ph + c2)*HWq;
        float f00 = __logf(fabsf(lb[jy*Hq + jx]) + 1.0f);
        float f01 = __logf(fabsf(lb[jy*Hq + nx]) + 1.0f);
        float f10 = __logf(fabsf(lb[ny*Hq + jx]) + 1.0f);
        float f11 = __logf(fabsf(lb[ny*Hq + nx]) + 1.0f);
        float f = 0.5625f*f00 + 0.1875f*(f01 + f10) + 0.0625f*f11;
        U[tb ? (c2*4*Hi + (g - off)*Hi + h) : (c2*4*Hi + g*4 + (h - off))] = f;
      }
      __syncthreads();
      if (valid){
        if (tb){
          #pragma unroll 1
          for (int ii = 0; ii < 2; ++ii){
            const float* wq = wl + (2*ph + ii)*200;
            const float* Ub = U + ii*4*Hi;
            #pragma unroll 1
            for (int p = 0; p < 5; ++p){
              int sy = y - 2 + p - off;
              if ((unsigned)sy >= 4u) continue;
              const float* Urow = Ub + sy*Hi;
              #pragma unroll
              for (int q = 0; q < 5; ++q){
                int h = x - 2 + q;
                if ((unsigned)h >= (unsigned)Hi) continue;
                float u = Urow[h];
                const v2f* wv = (const v2f*)(wq + (p*5+q)*8);
                #pragma unroll
                for (int o2 = 0; o2 < 4; ++o2) acc[o2] += wv[o2]*u;
              }
            }
          }
        } else {
          #pragma unroll 1
          for (int ii = 0; ii < 2; ++ii){
            const float* wq = wl + (2*ph + ii)*200;
            const float* Ub = U + ii*4*Hi;
            #pragma unroll 1
            for (int p = 0; p < 5; ++p){
              int g = y - 2 + p;
              const float* Urow = Ub + g*4;
              #pragma unroll
              for (int q = 0; q < 5; ++q){
                int h = x - 2 + q;
                int sx = h - off;
                if ((unsigned)sx >= 4u) continue;
                float u = Urow[sx];
                const v2f* wv = (const v2f*)(wq + (p*5+q)*8);
                #pragma unroll
                for (int o2 = 0; o2 < 4; ++o2) acc[o2] += wv[o2]*u;
              }
            }
          }
        }
      }
    }
    float lm[8];
    #pragma unroll
    for (int o = 0; o < 8; ++o) lm[o] = FINF;
    if (valid){
      #pragma unroll
      for (int o = 0; o < 8; ++o){
        float val = (o & 1) ? acc[o>>1].y : acc[o>>1].x;
        M[(size_t)(bl*8+o)*HW + (size_t)y*Hi + x] = f2b(val);
        lm[o] = fabsf(val);
      }
    }
    #pragma unroll
    for (int o = 0; o < 8; ++o){
      float v = lm[o];
      #pragma unroll
      for (int offw = 32; offw > 0; offw >>= 1) v = fminf(v, __shfl_xor(v, offw));
      if ((threadIdx.x & 63) == 0)
        atomicMin(mn + 2*maps + bl*8 + o, __float_as_uint(v));
    }
    return;
  }

  if (bid < g1){
    // --- convm fast path: 4x4-tap combined conv on quarter-res log tile.
    //     Shard: og=tid&3, hh=(tid>>2)&1, t8=tid>>3 -> row. Tile read as
    //     6 v2f pairs; weights per-lane v2f; FMA = v_pk_fma_f32 with
    //     op_sel broadcast of the tile word (bit-exact order). ---
    float* tile = smem;                       // [2][20][22] = 880
    float* wlds = smem + 880;                 // 2048 floats (parity block)
    const int idx = bid - gS;
    const int tiles = tprO*tprO;
    const int bl = idx / tiles;
    const int t  = idx - bl*tiles;
    const int Y0 = (t/tprO)*32, X0 = (t - (t/tprO)*tprO)*32;
    const int bg = b0 + bl;
    const float* bb = bm + (size_t)(s*64+bg)*8;
    const int Hi = 2*H;
    const int Hq = H, HWq = Hq*Hq;
    const int HW = Hi*Hi;
    const float* xb = X + (size_t)bl*8*HWq;
    const int R0 = (Y0>>1) - 2, C0 = (X0>>1) - 2;
    const int og = threadIdx.x & 3;           // o-pair (o = 2og, 2og+1)
    const int hh = (threadIdx.x >> 2) & 1;    // column half (16 cols)
    const int t8 = threadIdx.x >> 3;
    const int row = (t8 < 16) ? 2*t8 : 2*(t8-16)+1;   // wave-parity-uniform
    const int ty2 = (t8 < 16) ? t8 : (t8 - 16);
    const int par = __builtin_amdgcn_readfirstlane(row & 1);
    const float* w2b = w2 + ((size_t)(s*64+bg)*2 + par)*2048;

    // stage combined weights into LDS (once per block; 2 float4/thread)
    {
      const float4* wsrc = (const float4*)w2b;
      float4* wdst = (float4*)wlds;
      wdst[threadIdx.x] = wsrc[threadIdx.x];
      wdst[threadIdx.x + 256] = wsrc[threadIdx.x + 256];
    }

    v2f acc[16];                              // local col c; .x=o0 .y=o1
    {
      v2f b2; b2.x = bb[2*og]; b2.y = bb[2*og+1];
      #pragma unroll
      for (int c = 0; c < 16; ++c) acc[c] = b2;
    }
    float pre[4];
    #pragma unroll
    for (int k = 0; k < 4; ++k){
      int e = threadIdx.x + k*BLK;
      if (e < 800){
        int c2 = e/400; int r2 = e - 400*c2; int tr = r2/20; int tc = r2 - 20*tr;
        int ry = R0 + tr; ry = ry < 0 ? 0 : (ry >= Hq ? Hq-1 : ry);
        int rx = C0 + tc; rx = rx < 0 ? 0 : (rx >= Hq ? Hq-1 : rx);
        pre[k] = xb[(c2 ? HWq : 0) + ry*Hq + rx];
      }
    }
    #pragma unroll 1
    for (int ph = 0; ph < 4; ++ph){
      if (ph > 0) __syncthreads();
      #pragma unroll
      for (int k = 0; k < 4; ++k){
        int e = threadIdx.x + k*BLK;
        if (e < 800){
          int c2 = e/400; int r2 = e - 400*c2; int tr = r2/20; int tc = r2 - 20*tr;
          tile[c2*440 + tr*22 + tc] = __logf(fabsf(pre[k]) + 1.0f);
        }
      }
      __syncthreads();                        // also covers the weight staging
      if (ph < 3){
        const float* xn = xb + (size_t)((ph+1)*2)*HWq;
        #pragma unroll
        for (int k = 0; k < 4; ++k){
          int e = threadIdx.x + k*BLK;
          if (e < 800){
            int c2 = e/400; int r2 = e - 400*c2; int tr = r2/20; int tc = r2 - 20*tr;
            int ry = R0 + tr; ry = ry < 0 ? 0 : (ry >= Hq ? Hq-1 : ry);
            int rx = C0 + tc; rx = rx < 0 ? 0 : (rx >= Hq ? Hq-1 : rx);
            pre[k] = xn[(c2 ? HWq : 0) + ry*Hq + rx];
          }
        }
      }
      #pragma unroll
      for (int ii = 0; ii < 2; ++ii){
        const float* tch = tile + ii*440;
        const float* wB = wlds + (ph*2 + ii)*256;   // [tyT][px][t2][o]
        #pragma unroll
        for (int tyT = 0; tyT < 4; ++tyT){
          const float* rp = tch + (ty2 + par + tyT)*22 + 8*hh;
          v2f l2[6];
          #pragma unroll
          for (int j = 0; j < 6; ++j) l2[j] = *(const v2f*)(rp + 2*j);
          const float* wt_ = wB + tyT*64 + 2*og;
          #pragma unroll
          for (int t2 = 0; t2 < 4; ++t2){
            v2f we = *(const v2f*)(wt_ + t2*8);        // even-x (px=0)
            v2f wo = *(const v2f*)(wt_ + 32 + t2*8);   // odd-x  (px=1)
            #pragma unroll
            for (int cp = 0; cp < 8; ++cp){
              // acc[2cp]   += we * l[cp+t2]
              if ((cp + t2) & 1) { PK_HI(acc[2*cp], we, l2[(cp+t2)>>1]); }
              else               { PK_LO(acc[2*cp], we, l2[(cp+t2)>>1]); }
              // acc[2cp+1] += wo * l[cp+t2+1]
              if ((cp + t2 + 1) & 1) { PK_HI(acc[2*cp+1], wo, l2[(cp+t2+1)>>1]); }
              else                   { PK_LO(acc[2*cp+1], wo, l2[(cp+t2+1)>>1]); }
            }
          }
        }
      }
    }
    // epilogue: outputs at row y, cols X0+16*hh+c, channels 2og, 2og+1
    const int y = Y0 + row;
    const bool rowok = (unsigned)(y - 2) < (unsigned)(Hi - 4);
    const int xbase = X0 + 16*hh;
    const bool lbd = (xbase == 0);            // exclude local c = 0,1
    const bool rbd = (xbase + 16 == Hi);      // exclude local c = 14,15
    v2f mv2; mv2.x = FINF; mv2.y = FINF;
    if (rowok){
      #pragma unroll
      for (int c = 0; c < 16; ++c){
        bool skip = (lbd && c < 2) || (rbd && c >= 14);
        if (!skip){
          mv2.x = fminf(mv2.x, fabsf(acc[c].x));
          mv2.y = fminf(mv2.y, fabsf(acc[c].y));
        }
      }
    }
    #pragma unroll
    for (int offw = 4; offw < 64; offw <<= 1){
      mv2.x = fminf(mv2.x, __shfl_xor(mv2.x, offw));
      mv2.y = fminf(mv2.y, __shfl_xor(mv2.y, offw));
    }
    if ((threadIdx.x & 63) < 4){
      atomicMin(mn + 2*maps + bl*8 + 2*og,     __float_as_uint(mv2.x));
      atomicMin(mn + 2*maps + bl*8 + 2*og + 1, __float_as_uint(mv2.y));
    }
    if (rowok){
      #pragma unroll
      for (int oo = 0; oo < 2; ++oo){
        const int o = 2*og + oo;
        size_t base = (size_t)(bl*8+o)*HW + (size_t)y*Hi + xbase;
        #pragma unroll
        for (int gq = 0; gq < 4; ++gq){
          const int c0 = gq*4;
          if (lbd && gq == 0){
            float va = oo ? acc[2].y : acc[2].x;
            float vb2 = oo ? acc[3].y : acc[3].x;
            *(ushort2*)(M + base + 2) = make_ushort2(f2b(va), f2b(vb2));
          } else if (rbd && gq == 3){
            float va = oo ? acc[12].y : acc[12].x;
            float vb2 = oo ? acc[13].y : acc[13].x;
            *(ushort2*)(M + base + 12) = make_ushort2(f2b(va), f2b(vb2));
          } else {
            ushort4 h4 = make_ushort4(
              f2b(oo ? acc[c0].y   : acc[c0].x),
              f2b(oo ? acc[c0+1].y : acc[c0+1].x),
              f2b(oo ? acc[c0+2].y : acc[c0+2].x),
              f2b(oo ? acc[c0+3].y : acc[c0+3].x));
            *(ushort4*)(M + base + c0) = h4;
          }
        }
      }
    }
    return;
  }

  if (bid < g2){
    // ------- convt: 4x4 stride-2 transposed conv of (-x) (pad 1) -------
    //     Shard: og=tid&1, hh=(tid>>1)&3, t8=tid>>3 -> row. Tile NEGATED at
    //     staging so inner ops are += (exact); tile read as 3 v2f pairs;
    //     FMA = v_pk_fma_f32 with op_sel broadcast. ---
    float* tile = smem;                       // 8*18*20 = 2880
    float* wlds = smem + 2880;                // 1024 floats
    const int idx = bid - g1;
    const int tiles = tprO*tprO;
    const int bl = idx / tiles;
    const int t  = idx - bl*tiles;
    const int Y0 = (t/tprO)*32, X0 = (t - (t/tprO)*tprO)*32;  // output coords
    const int bg = b0 + bl;
    const float* wb = wt + (size_t)(s*64+bg)*1024;
    const float* bb = bt + (s*64+bg)*8;
    const int Ho = 2*H, HWo = Ho*Ho, HW = H*H;
    const float* xb = X + (size_t)bl*8*HW;
    const int ry0 = Y0/2 - 1, rx0 = X0/2 - 1;
    {
      // stage weights (1 float4/thread) + NEGATED input tile (two batches)
      ((float4*)wlds)[threadIdx.x] = ((const float4*)wb)[threadIdx.x];
      #pragma unroll 1
      for (int hb = 0; hb < 2; ++hb){
        float vb[6];
        #pragma unroll
        for (int k = 0; k < 6; ++k){
          int e = threadIdx.x + (hb*6 + k)*BLK;
          float v = 0.f;
          if (e < 2880){
            int cc = e % 20; int rr = (e/20) % 18; int ch = e/(20*18);
            int gy = ry0 + rr, gx = rx0 + cc;
            if (cc < 18 && (unsigned)gy < (unsigned)H && (unsigned)gx < (unsigned)H)
              v = xb[(size_t)ch*HW + gy*H + gx];
          }
          vb[k] = v;
        }
        #pragma unroll
        for (int k = 0; k < 6; ++k){
          int e = threadIdx.x + (hb*6 + k)*BLK;
          if (e < 2880) tile[e] = -vb[k];
        }
      }
    }
    __syncthreads();
    const int og = threadIdx.x & 1;           // channel quad (o = 4og+0..3)
    const int hh = (threadIdx.x >> 1) & 3;    // 8-col quarter
    const int t8 = threadIdx.x >> 3;
    const int row = (t8 < 16) ? 2*t8 : 2*(t8-16)+1;   // wave-parity-uniform
    const int yodd = __builtin_amdgcn_readfirstlane(row & 1);
    const int half = row >> 1;
    const int pA = yodd ? 0 : 1, rA = yodd ? half+2 : half+1;
    const int pB = yodd ? 2 : 3, rB = yodd ? half+1 : half;
    v2f acc[2][8];                            // [o-pair pp][local col]
    #pragma unroll
    for (int pp = 0; pp < 2; ++pp){
      v2f b2; b2.x = bb[4*og + 2*pp]; b2.y = bb[4*og + 2*pp + 1];
      #pragma unroll
      for (int c = 0; c < 8; ++c) acc[pp][c] = b2;
    }
    #pragma unroll 1
    for (int i = 0; i < 8; ++i){
      #pragma unroll
      for (int rt = 0; rt < 2; ++rt){
        const int p = rt ? pB : pA;
        const int ri = rt ? rB : rA;
        const float* rowp = tile + i*360 + ri*20 + 4*hh;
        v2f pa  = *(const v2f*)rowp;          // (-e0, -e1)
        v2f pb2 = *(const v2f*)(rowp + 2);    // (-e2, -e3)
        v2f pc  = *(const v2f*)(rowp + 4);    // (-e4, -e5)
        const float* wq = wlds + (i*4+p)*32 + 4*og;   // [q][o], per-lane
        #pragma unroll
        for (int pp = 0; pp < 2; ++pp){
          {
            v2f W1 = *(const v2f*)(wq + 8 + 2*pp);
            v2f W3 = *(const v2f*)(wq + 24 + 2*pp);
            // even cols: q1 then q3 (order preserved)
            PK_HI(acc[pp][0], W1, pa);  PK_LO(acc[pp][0], W3, pa);   // e1, e0
            PK_LO(acc[pp][2], W1, pb2); PK_HI(acc[pp][2], W3, pa);   // e2, e1
            PK_HI(acc[pp][4], W1, pb2); PK_LO(acc[pp][4], W3, pb2);  // e3, e2
            PK_LO(acc[pp][6], W1, pc);  PK_HI(acc[pp][6], W3, pb2);  // e4, e3
          }
          {
            v2f W0 = *(const v2f*)(wq + 2*pp);
            v2f W2 = *(const v2f*)(wq + 16 + 2*pp);
            // odd cols: q0 then q2
            PK_LO(acc[pp][1], W0, pb2); PK_HI(acc[pp][1], W2, pa);   // e2, e1
            PK_HI(acc[pp][3], W0, pb2); PK_LO(acc[pp][3], W2, pb2);  // e3, e2
            PK_LO(acc[pp][5], W0, pc);  PK_HI(acc[pp][5], W2, pb2);  // e4, e3
            PK_HI(acc[pp][7], W0, pc);  PK_LO(acc[pp][7], W2, pc);   // e5, e4
          }
        }
      }
    }
    // epilogue: outputs at row y, cols X0+8*hh+c, channels 4og+2pp+oo
    const int y = Y0 + row;
    const int xbase = X0 + 8*hh;
    v2f mv[2];
    mv[0].x = FINF; mv[0].y = FINF; mv[1].x = FINF; mv[1].y = FINF;
    #pragma unroll
    for (int pp = 0; pp < 2; ++pp)
      #pragma unroll
      for (int c = 0; c < 8; ++c){
        mv[pp].x = fminf(mv[pp].x, fabsf(acc[pp][c].x));
        mv[pp].y = fminf(mv[pp].y, fabsf(acc[pp][c].y));
      }
    #pragma unroll
    for (int offw = 2; offw < 64; offw <<= 1){
      #pragma unroll
      for (int pp = 0; pp < 2; ++pp){
        mv[pp].x = fminf(mv[pp].x, __shfl_xor(mv[pp].x, offw));
        mv[pp].y = fminf(mv[pp].y, __shfl_xor(mv[pp].y, offw));
      }
    }
    if ((threadIdx.x & 63) < 2){
      #pragma unroll
      for (int pp = 0; pp < 2; ++pp){
        atomicMin(mn + maps + bl*8 + 4*og + 2*pp,     __float_as_uint(mv[pp].x));
        atomicMin(mn + maps + bl*8 + 4*og + 2*pp + 1, __float_as_uint(mv[pp].y));
      }
    }
    #pragma unroll
    for (int pp = 0; pp < 2; ++pp){
      #pragma unroll
      for (int oo = 0; oo < 2; ++oo){
        const int o = 4*og + 2*pp + oo;
        size_t base = (size_t)(bl*8+o)*HWo + (size_t)y*Ho + xbase;
        ushort4 h4a = make_ushort4(
          f2b(oo ? acc[pp][0].y : acc[pp][0].x),
          f2b(oo ? acc[pp][1].y : acc[pp][1].x),
          f2b(oo ? acc[pp][2].y : acc[pp][2].x),
          f2b(oo ? acc[pp][3].y : acc[pp][3].x));
        *(ushort4*)(T + base) = h4a;
        ushort4 h4b = make_ushort4(
          f2b(oo ? acc[pp][4].y : acc[pp][4].x),
          f2b(oo ? acc[pp][5].y : acc[pp][5].x),
          f2b(oo ? acc[pp][6].y : acc[pp][6].x),
          f2b(oo ? acc[pp][7].y : acc[pp][7].x));
        *(ushort4*)(T + base + 4) = h4b;
      }
    }
    return;
  }

  {
    // --- convr: 3x3 (pad 1), FOUR phases of 2 ch. Shard: og=tid&1,
    //     hh=(tid>>1)&3, ty=tid>>3. Tile read as 5 v2f pairs; weights
    //     per-lane v2f; FMA = v_pk_fma_f32 with op_sel broadcast.
    //     Per-accumulator q-order (0,1,2) preserved (bit-exact). ---
    float* tile = smem;                       // 2*34*36 = 2448
    float* wlds = smem + 2448;                // 576 floats
    const int idx = bid - g2;
    const int tiles = tprR*tprR;
    const int bl = idx / tiles;
    const int t  = idx - bl*tiles;
    const int Y0 = (t/tprR)*32, X0 = (t - (t/tprR)*tprR)*32;
    const int bg = b0 + bl;
    const float* wb = wr + (size_t)(s*64+bg)*576;
    const float* bb = br + (s*64+bg)*8;
    const int HW = H*H;
    const float* xb = X + (size_t)bl*8*HW;
    const int og = threadIdx.x & 1;           // channel quad (o = 4og+0..3)
    const int hh = (threadIdx.x >> 1) & 3;    // 8-col octet
    const int ty = threadIdx.x >> 3;          // row
    const bool act = (Y0+ty < H) && (X0+8*hh < H);  // only false when H==16
    // stage weights into LDS (576 floats)
    #pragma unroll
    for (int k = 0; k < 3; ++k){
      int e = threadIdx.x + k*BLK;
      if (e < 576) wlds[e] = wb[e];
    }
    v2f acc[2][8];                            // [o-pair pp][local col]
    #pragma unroll
    for (int pp = 0; pp < 2; ++pp){
      v2f b2; b2.x = bb[4*og + 2*pp]; b2.y = bb[4*og + 2*pp + 1];
      #pragma unroll
      for (int c = 0; c < 8; ++c) acc[pp][c] = b2;
    }
    #pragma unroll 1
    for (int ph = 0; ph < 4; ++ph){
      if (ph > 0) __syncthreads();
      #pragma unroll 1
      for (int hb = 0; hb < 2; ++hb){
        float vb[5];
        #pragma unroll
        for (int k = 0; k < 5; ++k){
          int e = threadIdx.x + (hb*5 + k)*BLK;
          float v = 0.f;
          if (e < 2448){
            int cc = e % 36; int rr = (e/36) % 34; int c2 = e/(36*34);
            int gy = Y0 - 1 + rr, gx = X0 - 1 + cc;
            if (cc < 34 && (unsigned)gy < (unsigned)H && (unsigned)gx < (unsigned)H)
              v = xb[(size_t)(ph*2 + c2)*HW + gy*H + gx];
          }
          vb[k] = v;
        }
        #pragma unroll
        for (int k = 0; k < 5; ++k){
          int e = threadIdx.x + (hb*5 + k)*BLK;
          if (e < 2448) tile[e] = vb[k];
        }
      }
      __syncthreads();                        // also covers weight staging
      #pragma unroll 1
      for (int i = 0; i < 2; ++i){
        const float* tch = tile + i*1224;
        const int ig = ph*2 + i;
        #pragma unroll
        for (int p = 0; p < 3; ++p){
          const float* rowp = tch + (ty+p)*36 + 8*hh;
          v2f ep[5];
          #pragma unroll
          for (int j = 0; j < 5; ++j) ep[j] = *(const v2f*)(rowp + 2*j);
          const float* wq = wlds + (ig*3+p)*24 + 4*og;   // [q][o], per-lane
          #pragma unroll
          for (int q = 0; q < 3; ++q){
            #pragma unroll
            for (int pp = 0; pp < 2; ++pp){
              v2f W = *(const v2f*)(wq + q*8 + 2*pp);
              #pragma unroll
              for (int c = 0; c < 8; ++c){
                if ((c + q) & 1) { PK_HI(acc[pp][c], W, ep[(c+q)>>1]); }
                else             { PK_LO(acc[pp][c], W, ep[(c+q)>>1]); }
              }
            }
          }
        }
      }
    }
    // epilogue: outputs at row Y0+ty, cols X0+8*hh+c, channels 4og+2pp+oo
    v2f mv[2];
    mv[0].x = FINF; mv[0].y = FINF; mv[1].x = FINF; mv[1].y = FINF;
    if (act){
      #pragma unroll
      for (int pp = 0; pp < 2; ++pp)
        #pragma unroll
        for (int c = 0; c < 8; ++c){
          mv[pp].x = fminf(mv[pp].x, fabsf(acc[pp][c].x));
          mv[pp].y = fminf(mv[pp].y, fabsf(acc[pp][c].y));
        }
    }
    #pragma unroll
    for (int offw = 2; offw < 64; offw <<= 1){
      #pragma unroll
      for (int pp = 0; pp < 2; ++pp){
        mv[pp].x = fminf(mv[pp].x, __shfl_xor(mv[pp].x, offw));
        mv[pp].y = fminf(mv[pp].y, __shfl_xor(mv[pp].y, offw));
      }
    }
    if ((threadIdx.x & 63) < 2){
      #pragma unroll
      for (int pp = 0; pp < 2; ++pp){
        atomicMin(mn + bl*8 + 4*og + 2*pp,     __float_as_uint(mv[pp].x));
        atomicMin(mn + bl*8 + 4*og + 2*pp + 1, __float_as_uint(mv[pp].y));
      }
    }
    if (act){
      #pragma unroll
      for (int pp = 0; pp < 2; ++pp){
        #pragma unroll
        for (int oo = 0; oo < 2; ++oo){
          const int o = 4*og + 2*pp + oo;
          size_t base = (size_t)(bl*8+o)*HW + (size_t)(Y0+ty)*H + X0 + 8*hh;
          ushort4 h4a = make_ushort4(
            f2b(oo ? acc[pp][0].y : acc[pp][0].x),
            f2b(oo ? acc[pp][1].y : acc[pp][1].x),
            f2b(oo ? acc[pp][2].y : acc[pp][2].x),
            f2b(oo ? acc[pp][3].y : acc[pp][3].x));
          *(ushort4*)(D + base) = h4a;
          ushort4 h4b = make_ushort4(
            f2b(oo ? acc[pp][4].y : acc[pp][4].x),
            f2b(oo ? acc[pp][5].y : acc[pp][5].x),
            f2b(oo ? acc[pp][6].y : acc[pp][6].x),
            f2b(oo ? acc[pp][7].y : acc[pp][7].x));
          *(ushort4*)(D + base + 4) = h4b;
        }
      }
    }
  }
}

// s<3: next_x = (dln(Dr)[nearest-up] + dln(Dt)) * dln(Dm), into X. Quarter-px threads.
__global__ void combine_kernel(const unsigned short* __restrict__ dr,
                               const unsigned short* __restrict__ dt,
                               const unsigned short* __restrict__ dm,
                               const unsigned* __restrict__ mn, int maps,
                               float* __restrict__ outx, int H, int total){
  int Ho = 2*H, HWo = Ho*Ho, HW = H*H;
  for (int e = blockIdx.x*blockDim.x + threadIdx.x; e < total; e += gridDim.x*blockDim.x){
    int m = e / HW;
    int qpx = e - m*HW;
    int qy = qpx / H, qx = qpx - qy*H;
    float mr = __uint_as_float(mn[m]);
    float mt = __uint_as_float(mn[maps + m]);
    float mm = __uint_as_float(mn[2*maps + m]);
    float r = dln_one(b2f(dr[(size_t)m*HW + qpx]), mr);
    #pragma unroll
    for (int dy = 0; dy < 2; ++dy){
      size_t base = (size_t)m*HWo + (2*qy+dy)*Ho + 2*qx;
      ushort2 tv = *(const ushort2*)(dt + base);
      ushort2 mv = *(const ushort2*)(dm + base);
      float2 ov;
      ov.x = (r + dln_one(b2f(tv.x), mt)) * dln_one(b2f(mv.x), mm);
      ov.y = (r + dln_one(b2f(tv.y), mt)) * dln_one(b2f(mv.y), mm);
      *(float2*)(outx + base) = ov;
    }
  }
}

// s==3: combine + final dynamic 1x1 conv (8->3 ch) fused, writes d_out.
__global__ void combineF_kernel(const unsigned short* __restrict__ dr,
                                const unsigned short* __restrict__ dt,
                                const unsigned short* __restrict__ dm,
                                const unsigned* __restrict__ mn, int maps,
                                const float* __restrict__ wo, const float* __restrict__ bo,
                                float* __restrict__ out, int b0, int total){
  for (int e = blockIdx.x*blockDim.x + threadIdx.x; e < total; e += gridDim.x*blockDim.x){
    int bl = e >> 14;
    int qpx = e & 16383;
    int qy = qpx >> 7, qx = qpx & 127;
    int bg = b0 + bl;
    float r[8], mtv[8], mmv[8];
    #pragma unroll
    for (int o = 0; o < 8; ++o){
      int m = bl*8 + o;
      float mr = __uint_as_float(mn[m]);
      mtv[o] = __uint_as_float(mn[maps + m]);
      mmv[o] = __uint_as_float(mn[2*maps + m]);
      r[o] = dln_one(b2f(dr[(size_t)m*16384 + qpx]), mr);
    }
    #pragma unroll
    for (int dy = 0; dy < 2; ++dy){
      int y = 2*qy + dy, xx = 2*qx;
      float2 acc[3];
      #pragma unroll
      for (int of = 0; of < 3; ++of){
        float b = bo[bg*3 + of];
        acc[of].x = b; acc[of].y = b;
      }
      #pragma unroll
      for (int o = 0; o < 8; ++o){
        size_t base = (size_t)(bl*8+o)*65536 + y*256 + xx;
        ushort2 tv = *(const ushort2*)(dt + base);
        ushort2 mv = *(const ushort2*)(dm + base);
        float vx = (r[o] + dln_one(b2f(tv.x), mtv[o])) * dln_one(b2f(mv.x), mmv[o]);
        float vy = (r[o] + dln_one(b2f(tv.y), mtv[o])) * dln_one(b2f(mv.y), mmv[o]);
        #pragma unroll
        for (int of = 0; of < 3; ++of){
          float w = wo[bg*24 + of*8 + o];
          acc[of].x += w*vx; acc[of].y += w*vy;
        }
      }
      #pragma unroll
      for (int of = 0; of < 3; ++of){
        *(float2*)(out + ((size_t)(bg*3 + of))*65536 + y*256 + xx) = acc[of];
      }
    }
  }
}

static inline int grid_for(long long total){
  long long g = (total + BLK - 1) / BLK;
  if (g > 16384) g = 16384;
  if (g < 1) g = 1;
  return (int)g;
}

extern "C" void kernel_launch(void* const* d_in, const int* in_sizes, int n_in,
                              void* d_out, int out_size, void* d_ws, size_t ws_size,
                              hipStream_t stream){
  (void)in_sizes; (void)n_in; (void)out_size;
  const int*   ids   = (const int*)d_in[0];
  const float* cache = (const float*)d_in[1];
  const float* lat   = (const float*)d_in[2];
  const float* Wr = (const float*)d_in[3];
  const float* Ur = (const float*)d_in[4];
  const float* Vr = (const float*)d_in[5];
  const float* Br = (const float*)d_in[6];
  const float* Wt = (const float*)d_in[7];
  const float* Ut = (const float*)d_in[8];
  const float* Vt = (const float*)d_in[9];
  const float* Bt = (const float*)d_in[10];
  const float* Wm = (const float*)d_in[11];
  const float* Um = (const float*)d_in[12];
  const float* Vm = (const float*)d_in[13];
  const float* Bm = (const float*)d_in[14];
  const float* Wo = (const float*)d_in[15];
  const float* Uo = (const float*)d_in[16];
  const float* Vo = (const float*)d_in[17];
  const float* Bo = (const float*)d_in[18];
  float* out = (float*)d_out;
  float* ws  = (float*)d_ws;

  size_t off = 0;
  auto alloc = [&](size_t n){ size_t o = off; off += n; return o; };
  size_t o_ctx = alloc(2048);
  size_t o_ur = alloc(4*64*128),  o_vr = alloc(4*64*1152);
  size_t o_ut = alloc(4*64*128),  o_vt = alloc(4*64*2048);
  size_t o_um = alloc(4*64*128),  o_vm = alloc(4*64*3200);
  size_t o_br = alloc(4*64*8), o_bt = alloc(4*64*8), o_bm = alloc(4*64*8);
  size_t o_uo = alloc(64*48), o_vo = alloc(64*128), o_bo = alloc(64*3);
  size_t o_wr = alloc(4*64*8*72), o_wt = alloc(4*64*8*128), o_wm = alloc(4*64*8*200);
  size_t o_wo = alloc(64*24);
  size_t o_w2 = alloc((size_t)4*64*4096);   // combined convm weights
  size_t o_mn = alloc(4*3*512);             // [stage][3][maps]
  size_t small_end = off;

  // per sample (float units): X 131072 + D 65536 (bf16) + T 262144 + M 262144
  const size_t perS = 131072 + 65536 + 262144 + 262144;
  size_t ws_f = ws_size / sizeof(float);
  int nb = 64;
  while (nb > 1 && small_end + (size_t)nb*perS > ws_f) nb >>= 1;

  size_t o_X = small_end;
  size_t o_D = o_X + (size_t)nb*131072;
  size_t o_T = o_D + (size_t)nb*65536;
  size_t o_M = o_T + (size_t)nb*262144;
  unsigned* mn = (unsigned*)(ws + o_mn);
  unsigned short* Db = (unsigned short*)(ws + o_D);
  unsigned short* Tb = (unsigned short*)(ws + o_T);
  unsigned short* Mb = (unsigned short*)(ws + o_M);

  gather_ctx_kernel<<<8, BLK, 0, stream>>>(ids, cache, ws + o_ctx);

  W1Args a1;
  a1.M[0]=Ur;  a1.out[0]=ws+o_ur;
  a1.M[1]=Vr;  a1.out[1]=ws+o_vr;
  a1.M[2]=Ut;  a1.out[2]=ws+o_ut;
  a1.M[3]=Vt;  a1.out[3]=ws+o_vt;
  a1.M[4]=Um;  a1.out[4]=ws+o_um;
  a1.M[5]=Vm;  a1.out[5]=ws+o_vm;
  a1.M[6]=Br;  a1.out[6]=ws+o_br;
  a1.M[7]=Bt;  a1.out[7]=ws+o_bt;
  a1.M[8]=Bm;  a1.out[8]=ws+o_bm;
  a1.M[9]=Uo;  a1.out[9]=ws+o_uo;
  a1.M[10]=Vo; a1.out[10]=ws+o_vo;
  a1.M[11]=Bo; a1.out[11]=ws+o_bo;
  w1_kernel<<<256, BLK, 0, stream>>>(ws + o_ctx, a1);

  W2Args a2;
  a2.W[0]=Wr; a2.u[0]=ws+o_ur; a2.v[0]=ws+o_vr; a2.out[0]=ws+o_wr;
  a2.W[1]=Wt; a2.u[1]=ws+o_ut; a2.v[1]=ws+o_vt; a2.out[1]=ws+o_wt;
  a2.W[2]=Wm; a2.u[2]=ws+o_um; a2.v[2]=ws+o_vm; a2.out[2]=ws+o_wm;
  a2.W[3]=Wo; a2.u[3]=ws+o_uo; a2.v[3]=ws+o_vo; a2.out[3]=ws+o_wo;
  w2_kernel<<<256, BLK, 0, stream>>>(a2);

  w4_kernel<<<64, BLK, 0, stream>>>(ws + o_wm, ws + o_w2);

  for (int b0 = 0; b0 < 64; b0 += nb){
    gather_x_kernel<<<grid_for((long long)nb*2048), BLK, 0, stream>>>(
        ids, lat, ws+o_X, b0, nb);
    int maps = nb*8;
    init_min_kernel<<<(4*3*maps + BLK-1)/BLK, BLK, 0, stream>>>(mn, 4*3*maps);
    int H = 16;
    for (int s = 0; s < 4; ++s){
      int Ho = 2*H;
      int tprR = (H >= 32) ? H/32 : 1;
      int tprO = Ho/32;
      int gR = nb*tprR*tprR;
      int gT = nb*tprO*tprO;
      int gM = nb*tprO*tprO;
      int gSN = 8*nb;                          // strips first (1 px/thread)
      int g1 = gSN + gM, g2 = g1 + gT;         // then convm, convt, convr
      unsigned* mns = mn + (size_t)s*3*maps;
      conv3_fused<<<g2 + gR, BLK, 0, stream>>>(
          ws+o_X, ws+o_wr, ws+o_br, ws+o_wt, ws+o_bt, ws+o_wm, ws+o_bm,
          ws+o_w2, Db, Tb, Mb, mns, maps, H, b0, s, tprR, tprO, gSN, g1, g2);
      if (s < 3){
        long long totalq = (long long)maps*H*H;
        combine_kernel<<<grid_for(totalq), BLK, 0, stream>>>(
            Db, Tb, Mb, mns, maps, ws+o_X, H, (int)totalq);
      } else {
        long long totalf = (long long)nb*16384;
        combineF_kernel<<<grid_for(totalf), BLK, 0, stream>>>(
            Db, Tb, Mb, mns, maps, ws+o_wo, ws+o_bo, out, b0, (int)totalf);
      }
      H = Ho;
    }
  }
}

// Round 16
// 582.888 us; speedup vs baseline: 1.0058x; 1.0058x over previous
//
#include <hip/hip_runtime.h>
#include <math.h>

// ExperimentalModel_1752346656819: 4-stage dynamic-conv decoder, fp32 compute.
// R31 = R30 = R28 (resubmit; Round-15 bench was an infra failure: "MI355X
// container failed twice" -- no kernel signal). R28 is the session best
// (583.3us measured, from 815.6 baseline): quarter-res convm (R16/R21),
// 48-VGPR occupancy tier (R24), per-lane LDS weight shard in all three
// conv branches (R26/R27/R28). Profile at rest: VALU 58%, HBM 18%, occ 47%.

#define BLK 256
#define EF 2.7182818284590452f
#define FINF 3.4e38f

typedef float v2f __attribute__((ext_vector_type(2)));

struct W1Args { const float* M[12]; float* out[12]; };
struct W2Args { const float* W[4]; const float* u[4]; const float* v[4]; float* out[4]; };

__device__ __forceinline__ unsigned short f2b(float f){
  unsigned u = __float_as_uint(f);
  unsigned r = u + 0x7FFFu + ((u >> 16) & 1u);   // round-to-nearest-even
  return (unsigned short)(r >> 16);
}
__device__ __forceinline__ float b2f(unsigned short h){
  return __uint_as_float((unsigned)h << 16);
}
__device__ __forceinline__ v2f mkv(float a, float b){ v2f r; r.x=a; r.y=b; return r; }

__device__ __forceinline__ float dln_one(float y, float m){
  float a = fabsf(y) - m;
  float v = __logf(__logf(a + EF) + 0.01f);
  return (y > 0.0f) ? v : -v;
}

__global__ void gather_ctx_kernel(const int* __restrict__ ids,
                                  const float* __restrict__ cache,
                                  float* __restrict__ ctx){
  int e = blockIdx.x*blockDim.x + threadIdx.x;
  if (e < 64*32){
    int b = e >> 5, l = e & 31;
    ctx[e] = cache[(size_t)ids[b]*32 + l];
  }
}

__global__ void gather_x_kernel(const int* __restrict__ ids,
                                const float* __restrict__ lat,
                                float* __restrict__ X, int b0, int nb){
  int total = nb*2048;
  int e = blockIdx.x*blockDim.x + threadIdx.x;
  if (e < total){
    int bl = e >> 11;
    int r  = e & 2047;
    X[e] = lat[(size_t)ids[b0+bl]*2048 + r];
  }
}

__global__ void w1_kernel(const float* __restrict__ ctx, W1Args args){
  const int S[12] = {4,4,4,4,4,4,4,4,4,1,1,1};
  const int K[12] = {128,1152,128,2048,128,3200,8,8,8,48,128,3};
  int tid = blockIdx.x*blockDim.x + threadIdx.x;
  int nth = gridDim.x*blockDim.x;
  for (int seg = 0; seg < 12; ++seg){
    const float* M = args.M[seg];
    float* out = args.out[seg];
    int Ks = K[seg];
    int total = S[seg]*64*Ks;
    for (int e = tid; e < total; e += nth){
      int k = e % Ks;
      int b = (e / Ks) % 64;
      int s = e / (Ks*64);
      const float* Ms = M + (size_t)s*32*Ks + k;
      const float* cb = ctx + b*32;
      float acc = 0.f;
      #pragma unroll
      for (int l = 0; l < 32; ++l) acc += cb[l]*Ms[(size_t)l*Ks];
      out[e] = acc;
    }
  }
}

// Dynamic weights. Segs 0-2 TRANSPOSED to [s][b][i][p][q][o]; seg 3 [b][o][i].
__global__ void w2_kernel(W2Args args){
  const int S[4] = {4,4,4,1};
  const int O[4] = {8,8,8,3};
  const int K[4] = {72,128,200,8};
  const int KH[4] = {3,4,5,1};
  int tid = blockIdx.x*blockDim.x + threadIdx.x;
  int nth = gridDim.x*blockDim.x;
  for (int seg = 0; seg < 4; ++seg){
    int Os = O[seg], Ks = K[seg];
    int kh = KH[seg], kk = kh*kh;
    int total = S[seg]*64*Os*Ks;
    const float* Wt = args.W[seg];
    const float* u = args.u[seg];
    const float* v = args.v[seg];
    float* out = args.out[seg];
    for (int e = tid; e < total; e += nth){
      int k = e % Ks;
      int o = (e/Ks) % Os;
      int b = (e/(Ks*Os)) % 64;
      int s = e/(Ks*Os*64);
      const float* us = u + (size_t)(s*64+b)*16*Os;
      const float* vs = v + (size_t)(s*64+b)*16*Ks;
      float mod = 0.f;
      #pragma unroll
      for (int r = 0; r < 16; ++r) mod += us[r*Os+o]*vs[r*Ks+k];
      float val = Wt[(size_t)(s*Os+o)*Ks + k] * (1.0f + mod + 1e-3f);
      size_t dst;
      if (seg < 3){
        int i = k / kk, r2 = k - i*kk, p = r2 / kh, q = r2 - p*kh;
        dst = (size_t)(s*64+b)*(8*Ks) + (size_t)(((i*kh+p)*kh+q)*8 + o);
      } else {
        dst = (size_t)b*24 + o*8 + k;
      }
      out[dst] = val;
    }
  }
}

// Combined bilinear-upsample x conv5x5 weights on the quarter-res grid.
// For each (s,b,i,o): W2[py][tyT][px][txT] = sum_{p,q} A(py)[tyT][p] K[p][q] A(px)[txT][q]
// Layout: w2[(sb*2+py)*2048 + i*256 + tyT*64 + px*32 + txT*8 + o]
__global__ void w4_kernel(const float* __restrict__ wmdyn, float* __restrict__ w2o){
  int e = blockIdx.x*blockDim.x + threadIdx.x;
  if (e >= 16384) return;          // 4 stages * 64 samples * 8 i * 8 o
  int o = e & 7, i = (e >> 3) & 7, sb = e >> 6;
  const float* wk = wmdyn + (size_t)sb*1600 + i*200 + o;
  float K[5][5];
  #pragma unroll
  for (int p = 0; p < 5; ++p)
    #pragma unroll
    for (int q = 0; q < 5; ++q) K[p][q] = wk[(p*5+q)*8];
  const float Ae[4][5] = {{0.25f,0.f,0.f,0.f,0.f},
                          {0.75f,0.75f,0.25f,0.f,0.f},
                          {0.f,0.25f,0.75f,0.75f,0.25f},
                          {0.f,0.f,0.f,0.25f,0.75f}};
  const float Ao[4][5] = {{0.75f,0.25f,0.f,0.f,0.f},
                          {0.25f,0.75f,0.75f,0.25f,0.f},
                          {0.f,0.f,0.25f,0.75f,0.75f},
                          {0.f,0.f,0.f,0.f,0.25f}};
  #pragma unroll
  for (int py = 0; py < 2; ++py){
    float T[4][5];
    #pragma unroll
    for (int ty = 0; ty < 4; ++ty)
      #pragma unroll
      for (int q = 0; q < 5; ++q){
        float a = 0.f;
        #pragma unroll
        for (int p = 0; p < 5; ++p) a += (py ? Ao[ty][p] : Ae[ty][p]) * K[p][q];
        T[ty][q] = a;
      }
    #pragma unroll
    for (int ty = 0; ty < 4; ++ty)
      #pragma unroll
      for (int px = 0; px < 2; ++px)
        #pragma unroll
        for (int tx = 0; tx < 4; ++tx){
          float a = 0.f;
          #pragma unroll
          for (int q = 0; q < 5; ++q) a += T[ty][q] * (px ? Ao[tx][q] : Ae[tx][q]);
          w2o[(size_t)(sb*2+py)*2048 + i*256 + ty*64 + px*32 + tx*8 + o] = a;
        }
  }
}

__global__ void init_min_kernel(unsigned* __restrict__ mn, int n){
  int e = blockIdx.x*blockDim.x + threadIdx.x;
  if (e < n) mn[e] = 0x7F800000u;   // +inf
}

// Fused per-stage conv kernel. Grid:
// [0,gS)     convm border strips (exact 5x5, ONE px/thread, weights in LDS)
// [gS,g1)    convm (quarter-res combined 4x4, per-lane weights: o-pair shard)
// [g1,g2)    convt (4x4 T, per-lane weights: channel-quad shard)
// [g2,..)    convr (3x3, per-lane weights: channel-quad shard)
// Outputs D/T/M in bf16. LDS union 15.6 KB.
__attribute__((amdgpu_num_vgpr(48)))
__global__ void __launch_bounds__(BLK) conv3_fused(
    const float* __restrict__ X,
    const float* __restrict__ wr, const float* __restrict__ br,
    const float* __restrict__ wt, const float* __restrict__ bt,
    const float* __restrict__ wm, const float* __restrict__ bm,
    const float* __restrict__ w2,
    unsigned short* __restrict__ D, unsigned short* __restrict__ T,
    unsigned short* __restrict__ M,
    unsigned* __restrict__ mn, int maps, int H, int b0, int s,
    int tprR, int tprO, int gS, int g1, int g2){
  __shared__ __align__(16) float smem[3904];
  const int bid = blockIdx.x;

  if (bid < gS){
    // --- convm border strips: exact 5x5 on bilinear-up(log) with zero-pad.
    //     8 blocks/sample: side (0/1 rows, 2/3 cols) x 2 sub-blocks.
    //     ONE output px per thread: acc[4] v2f, (y,x,valid) precomputed.
    //     U strip + 1600 dyn weights in LDS. ---
    float* U  = smem;                         // 2*4*Hi <= 2048
    float* wl = smem + 2048;                  // 1600 floats
    const int bl = bid >> 3;
    const int r3 = bid & 7;
    const int side = r3 >> 1;
    const int kblk = r3 & 1;
    const int bg = b0 + bl;
    const int Hi = 2*H, Hq = H, HWq = Hq*Hq, HW = Hi*Hi;
    const float* wb = wm + (size_t)(s*64+bg)*1600;   // [i][p][q][o], o contig
    const float* bb = bm + (size_t)(s*64+bg)*8;
    const float* xb = X + (size_t)bl*8*HWq;
    const bool tb = (side < 2);
    const int off = (side & 1) ? Hi - 4 : 0;
    const int cnt = tb ? 2*Hi : 2*(Hi - 4);
    const int hsh = 31 - __clz(Hi);
    // stage weights (covered by the syncthreads after the first U build)
    #pragma unroll
    for (int k = 0; k < 7; ++k){
      int e = threadIdx.x + k*BLK;
      if (e < 1600) wl[e] = wb[e];
    }
    const int e2 = kblk*BLK + (int)threadIdx.x;
    const bool valid = e2 < cnt;
    int y, x;
    if (tb){
      int yl = (e2 >= Hi) ? 1 : 0;
      x = e2 - yl*Hi;
      y = (side == 0) ? yl : (Hi - 2 + yl);
    } else {
      int xl2 = (e2 >= Hi - 4) ? 1 : 0;
      y = 2 + e2 - xl2*(Hi - 4);
      x = (side == 2) ? xl2 : (Hi - 2 + xl2);
    }
    v2f acc[4];
    #pragma unroll
    for (int o2 = 0; o2 < 4; ++o2){
      v2f b2; b2.x = bb[2*o2]; b2.y = bb[2*o2+1];
      acc[o2] = b2;
    }
    const int elems = 8*Hi;
    #pragma unroll 1
    for (int ph = 0; ph < 4; ++ph){
      if (ph > 0) __syncthreads();
      #pragma unroll 1
      for (int e = threadIdx.x; e < elems; e += BLK){
        int c2 = (e >= 4*Hi) ? 1 : 0;
        int r = e - c2*4*Hi;
        int g, h;
        if (tb){ g = off + (r >> hsh); h = r & (Hi - 1); }
        else   { g = r >> 2;           h = off + (r & 3); }
        int jy = g >> 1;
        int ny = (g & 1) ? ((jy+1 < Hq) ? jy+1 : Hq-1) : ((jy > 0) ? jy-1 : 0);
        int jx = h >> 1;
        int nx = (h & 1) ? ((jx+1 < Hq) ? jx+1 : Hq-1) : ((jx > 0) ? jx-1 : 0);
        const float* lb = xb + (size_t)(2*ph + c2)*HWq;
        float f00 = __logf(fabsf(lb[jy*Hq + jx]) + 1.0f);
        float f01 = __logf(fabsf(lb[jy*Hq + nx]) + 1.0f);
        float f10 = __logf(fabsf(lb[ny*Hq + jx]) + 1.0f);
        float f11 = __logf(fabsf(lb[ny*Hq + nx]) + 1.0f);
        float f = 0.5625f*f00 + 0.1875f*(f01 + f10) + 0.0625f*f11;
        U[tb ? (c2*4*Hi + (g - off)*Hi + h) : (c2*4*Hi + g*4 + (h - off))] = f;
      }
      __syncthreads();
      if (valid){
        if (tb){
          #pragma unroll 1
          for (int ii = 0; ii < 2; ++ii){
            const float* wq = wl + (2*ph + ii)*200;
            const float* Ub = U + ii*4*Hi;
            #pragma unroll 1
            for (int p = 0; p < 5; ++p){
              int sy = y - 2 + p - off;
              if ((unsigned)sy >= 4u) continue;
              const float* Urow = Ub + sy*Hi;
              #pragma unroll
              for (int q = 0; q < 5; ++q){
                int h = x - 2 + q;
                if ((unsigned)h >= (unsigned)Hi) continue;
                float u = Urow[h];
                const v2f* wv = (const v2f*)(wq + (p*5+q)*8);
                #pragma unroll
                for (int o2 = 0; o2 < 4; ++o2) acc[o2] += wv[o2]*u;
              }
            }
          }
        } else {
          #pragma unroll 1
          for (int ii = 0; ii < 2; ++ii){
            const float* wq = wl + (2*ph + ii)*200;
            const float* Ub = U + ii*4*Hi;
            #pragma unroll 1
            for (int p = 0; p < 5; ++p){
              int g = y - 2 + p;
              const float* Urow = Ub + g*4;
              #pragma unroll
              for (int q = 0; q < 5; ++q){
                int h = x - 2 + q;
                int sx = h - off;
                if ((unsigned)sx >= 4u) continue;
                float u = Urow[sx];
                const v2f* wv = (const v2f*)(wq + (p*5+q)*8);
                #pragma unroll
                for (int o2 = 0; o2 < 4; ++o2) acc[o2] += wv[o2]*u;
              }
            }
          }
        }
      }
    }
    float lm[8];
    #pragma unroll
    for (int o = 0; o < 8; ++o) lm[o] = FINF;
    if (valid){
      #pragma unroll
      for (int o = 0; o < 8; ++o){
        float val = (o & 1) ? acc[o>>1].y : acc[o>>1].x;
        M[(size_t)(bl*8+o)*HW + (size_t)y*Hi + x] = f2b(val);
        lm[o] = fabsf(val);
      }
    }
    #pragma unroll
    for (int o = 0; o < 8; ++o){
      float v = lm[o];
      #pragma unroll
      for (int offw = 32; offw > 0; offw >>= 1) v = fminf(v, __shfl_xor(v, offw));
      if ((threadIdx.x & 63) == 0)
        atomicMin(mn + 2*maps + bl*8 + o, __float_as_uint(v));
    }
    return;
  }

  if (bid < g1){
    // --- convm fast path: 4x4-tap combined conv on quarter-res log tile.
    //     Thread shard: og=tid&3 (o-pair), hh=(tid>>2)&1 (16-col half),
    //     t8=tid>>3 -> row (wave-parity-uniform). Each thread: 2 ch x 16
    //     cols of one row (acc 16 v2f). Weight reads PER-LANE (+2*og).
    //     Exact for y,x in [2, Hi-2); border px handled by strips blocks. ---
    float* tile = smem;                       // [2][20][22] = 880
    float* wlds = smem + 880;                 // 2048 floats (parity block)
    const int idx = bid - gS;
    const int tiles = tprO*tprO;
    const int bl = idx / tiles;
    const int t  = idx - bl*tiles;
    const int Y0 = (t/tprO)*32, X0 = (t - (t/tprO)*tprO)*32;
    const int bg = b0 + bl;
    const float* bb = bm + (size_t)(s*64+bg)*8;
    const int Hi = 2*H;
    const int Hq = H, HWq = Hq*Hq;
    const int HW = Hi*Hi;
    const float* xb = X + (size_t)bl*8*HWq;
    const int R0 = (Y0>>1) - 2, C0 = (X0>>1) - 2;
    const int og = threadIdx.x & 3;           // o-pair (o = 2og, 2og+1)
    const int hh = (threadIdx.x >> 2) & 1;    // column half (16 cols)
    const int t8 = threadIdx.x >> 3;
    const int row = (t8 < 16) ? 2*t8 : 2*(t8-16)+1;   // wave-parity-uniform
    const int ty2 = (t8 < 16) ? t8 : (t8 - 16);
    const int par = __builtin_amdgcn_readfirstlane(row & 1);
    const float* w2b = w2 + ((size_t)(s*64+bg)*2 + par)*2048;

    // stage combined weights into LDS (once per block; 2 float4/thread)
    {
      const float4* wsrc = (const float4*)w2b;
      float4* wdst = (float4*)wlds;
      wdst[threadIdx.x] = wsrc[threadIdx.x];
      wdst[threadIdx.x + 256] = wsrc[threadIdx.x + 256];
    }

    v2f acc[16];                              // local col c; .x=o0 .y=o1
    {
      v2f b2; b2.x = bb[2*og]; b2.y = bb[2*og+1];
      #pragma unroll
      for (int c = 0; c < 16; ++c) acc[c] = b2;
    }
    float pre[4];
    #pragma unroll
    for (int k = 0; k < 4; ++k){
      int e = threadIdx.x + k*BLK;
      if (e < 800){
        int c2 = e/400; int r2 = e - 400*c2; int tr = r2/20; int tc = r2 - 20*tr;
        int ry = R0 + tr; ry = ry < 0 ? 0 : (ry >= Hq ? Hq-1 : ry);
        int rx = C0 + tc; rx = rx < 0 ? 0 : (rx >= Hq ? Hq-1 : rx);
        pre[k] = xb[(c2 ? HWq : 0) + ry*Hq + rx];
      }
    }
    #pragma unroll 1
    for (int ph = 0; ph < 4; ++ph){
      if (ph > 0) __syncthreads();
      #pragma unroll
      for (int k = 0; k < 4; ++k){
        int e = threadIdx.x + k*BLK;
        if (e < 800){
          int c2 = e/400; int r2 = e - 400*c2; int tr = r2/20; int tc = r2 - 20*tr;
          tile[c2*440 + tr*22 + tc] = __logf(fabsf(pre[k]) + 1.0f);
        }
      }
      __syncthreads();                        // also covers the weight staging
      if (ph < 3){
        const float* xn = xb + (size_t)((ph+1)*2)*HWq;
        #pragma unroll
        for (int k = 0; k < 4; ++k){
          int e = threadIdx.x + k*BLK;
          if (e < 800){
            int c2 = e/400; int r2 = e - 400*c2; int tr = r2/20; int tc = r2 - 20*tr;
            int ry = R0 + tr; ry = ry < 0 ? 0 : (ry >= Hq ? Hq-1 : ry);
            int rx = C0 + tc; rx = rx < 0 ? 0 : (rx >= Hq ? Hq-1 : rx);
            pre[k] = xn[(c2 ? HWq : 0) + ry*Hq + rx];
          }
        }
      }
      #pragma unroll
      for (int ii = 0; ii < 2; ++ii){
        const float* tch = tile + ii*440;
        const float* wB = wlds + (ph*2 + ii)*256;   // [tyT][px][t2][o]
        #pragma unroll
        for (int tyT = 0; tyT < 4; ++tyT){
          const float* rp = tch + (ty2 + par + tyT)*22 + 8*hh;
          float l[12];
          #pragma unroll
          for (int j = 0; j < 6; ++j){
            float2 p = *(const float2*)(rp + 2*j);
            l[2*j] = p.x; l[2*j+1] = p.y;
          }
          const float* wt_ = wB + tyT*64 + 2*og;
          #pragma unroll
          for (int t2 = 0; t2 < 4; ++t2){
            v2f we = *(const v2f*)(wt_ + t2*8);        // even-x (px=0)
            v2f wo = *(const v2f*)(wt_ + 32 + t2*8);   // odd-x  (px=1)
            #pragma unroll
            for (int cp = 0; cp < 8; ++cp){
              acc[2*cp]   += we * l[cp + t2];
              acc[2*cp+1] += wo * l[cp + t2 + 1];
            }
          }
        }
      }
    }
    // epilogue: outputs at row y, cols X0+16*hh+c, channels 2og, 2og+1
    const int y = Y0 + row;
    const bool rowok = (unsigned)(y - 2) < (unsigned)(Hi - 4);
    const int xbase = X0 + 16*hh;
    const bool lbd = (xbase == 0);            // exclude local c = 0,1
    const bool rbd = (xbase + 16 == Hi);      // exclude local c = 14,15
    v2f mv2; mv2.x = FINF; mv2.y = FINF;
    if (rowok){
      #pragma unroll
      for (int c = 0; c < 16; ++c){
        bool skip = (lbd && c < 2) || (rbd && c >= 14);
        if (!skip){
          mv2.x = fminf(mv2.x, fabsf(acc[c].x));
          mv2.y = fminf(mv2.y, fabsf(acc[c].y));
        }
      }
    }
    #pragma unroll
    for (int offw = 4; offw < 64; offw <<= 1){
      mv2.x = fminf(mv2.x, __shfl_xor(mv2.x, offw));
      mv2.y = fminf(mv2.y, __shfl_xor(mv2.y, offw));
    }
    if ((threadIdx.x & 63) < 4){
      atomicMin(mn + 2*maps + bl*8 + 2*og,     __float_as_uint(mv2.x));
      atomicMin(mn + 2*maps + bl*8 + 2*og + 1, __float_as_uint(mv2.y));
    }
    if (rowok){
      #pragma unroll
      for (int oo = 0; oo < 2; ++oo){
        const int o = 2*og + oo;
        size_t base = (size_t)(bl*8+o)*HW + (size_t)y*Hi + xbase;
        #pragma unroll
        for (int gq = 0; gq < 4; ++gq){
          const int c0 = gq*4;
          if (lbd && gq == 0){
            float va = oo ? acc[2].y : acc[2].x;
            float vb2 = oo ? acc[3].y : acc[3].x;
            *(ushort2*)(M + base + 2) = make_ushort2(f2b(va), f2b(vb2));
          } else if (rbd && gq == 3){
            float va = oo ? acc[12].y : acc[12].x;
            float vb2 = oo ? acc[13].y : acc[13].x;
            *(ushort2*)(M + base + 12) = make_ushort2(f2b(va), f2b(vb2));
          } else {
            ushort4 h4 = make_ushort4(
              f2b(oo ? acc[c0].y   : acc[c0].x),
              f2b(oo ? acc[c0+1].y : acc[c0+1].x),
              f2b(oo ? acc[c0+2].y : acc[c0+2].x),
              f2b(oo ? acc[c0+3].y : acc[c0+3].x));
            *(ushort4*)(M + base + c0) = h4;
          }
        }
      }
    }
    return;
  }

  if (bid < g2){
    // ------- convt: 4x4 stride-2 transposed conv of (-x) (pad 1) -------
    //     Thread shard: og=tid&1 (channel quad o=4og+0..3), hh=(tid>>1)&3
    //     (8-col quarter), t8=tid>>3 -> row (wave-parity map). Each thread:
    //     4 ch x 8 cols x 1 row (acc[2][8] v2f). Weights PER-LANE
    //     (+4og+2pp); tile 3x float2. ---
    float* tile = smem;                       // 8*18*20 = 2880
    float* wlds = smem + 2880;                // 1024 floats
    const int idx = bid - g1;
    const int tiles = tprO*tprO;
    const int bl = idx / tiles;
    const int t  = idx - bl*tiles;
    const int Y0 = (t/tprO)*32, X0 = (t - (t/tprO)*tprO)*32;  // output coords
    const int bg = b0 + bl;
    const float* wb = wt + (size_t)(s*64+bg)*1024;
    const float* bb = bt + (s*64+bg)*8;
    const int Ho = 2*H, HWo = Ho*Ho, HW = H*H;
    const float* xb = X + (size_t)bl*8*HW;
    const int ry0 = Y0/2 - 1, rx0 = X0/2 - 1;
    {
      // stage weights (1 float4/thread) + input tile in two 6-reg batches
      ((float4*)wlds)[threadIdx.x] = ((const float4*)wb)[threadIdx.x];
      #pragma unroll 1
      for (int hb = 0; hb < 2; ++hb){
        float vb[6];
        #pragma unroll
        for (int k = 0; k < 6; ++k){
          int e = threadIdx.x + (hb*6 + k)*BLK;
          float v = 0.f;
          if (e < 2880){
            int cc = e % 20; int rr = (e/20) % 18; int ch = e/(20*18);
            int gy = ry0 + rr, gx = rx0 + cc;
            if (cc < 18 && (unsigned)gy < (unsigned)H && (unsigned)gx < (unsigned)H)
              v = xb[(size_t)ch*HW + gy*H + gx];
          }
          vb[k] = v;
        }
        #pragma unroll
        for (int k = 0; k < 6; ++k){
          int e = threadIdx.x + (hb*6 + k)*BLK;
          if (e < 2880) tile[e] = vb[k];
        }
      }
    }
    __syncthreads();
    const int og = threadIdx.x & 1;           // channel quad (o = 4og+0..3)
    const int hh = (threadIdx.x >> 1) & 3;    // 8-col quarter
    const int t8 = threadIdx.x >> 3;
    const int row = (t8 < 16) ? 2*t8 : 2*(t8-16)+1;   // wave-parity-uniform
    const int yodd = __builtin_amdgcn_readfirstlane(row & 1);
    const int half = row >> 1;
    const int pA = yodd ? 0 : 1, rA = yodd ? half+2 : half+1;
    const int pB = yodd ? 2 : 3, rB = yodd ? half+1 : half;
    v2f acc[2][8];                            // [o-pair pp][local col]
    #pragma unroll
    for (int pp = 0; pp < 2; ++pp){
      v2f b2; b2.x = bb[4*og + 2*pp]; b2.y = bb[4*og + 2*pp + 1];
      #pragma unroll
      for (int c = 0; c < 8; ++c) acc[pp][c] = b2;
    }
    #pragma unroll 1
    for (int i = 0; i < 8; ++i){
      #pragma unroll
      for (int rt = 0; rt < 2; ++rt){
        const int p = rt ? pB : pA;
        const int ri = rt ? rB : rA;
        const float* rowp = tile + i*360 + ri*20 + 4*hh;
        float2 pa = *(const float2*)rowp;
        float2 pb2 = *(const float2*)(rowp + 2);
        float2 pc = *(const float2*)(rowp + 4);
        float e0 = pa.x, e1 = pa.y, e2 = pb2.x, e3 = pb2.y, e4 = pc.x, e5 = pc.y;
        const float* wq = wlds + (i*4+p)*32 + 4*og;   // [q][o], per-lane
        #pragma unroll
        for (int pp = 0; pp < 2; ++pp){
          {
            v2f W1 = *(const v2f*)(wq + 8 + 2*pp);
            v2f W3 = *(const v2f*)(wq + 24 + 2*pp);
            acc[pp][0] -= W1*e1; acc[pp][0] -= W3*e0;   // even cols: q1 then q3
            acc[pp][2] -= W1*e2; acc[pp][2] -= W3*e1;
            acc[pp][4] -= W1*e3; acc[pp][4] -= W3*e2;
            acc[pp][6] -= W1*e4; acc[pp][6] -= W3*e3;
          }
          {
            v2f W0 = *(const v2f*)(wq + 2*pp);
            v2f W2 = *(const v2f*)(wq + 16 + 2*pp);
            acc[pp][1] -= W0*e2; acc[pp][1] -= W2*e1;   // odd cols: q0 then q2
            acc[pp][3] -= W0*e3; acc[pp][3] -= W2*e2;
            acc[pp][5] -= W0*e4; acc[pp][5] -= W2*e3;
            acc[pp][7] -= W0*e5; acc[pp][7] -= W2*e4;
          }
        }
      }
    }
    // epilogue: outputs at row y, cols X0+8*hh+c, channels 4og+2pp+oo
    const int y = Y0 + row;
    const int xbase = X0 + 8*hh;
    v2f mv[2];
    mv[0].x = FINF; mv[0].y = FINF; mv[1].x = FINF; mv[1].y = FINF;
    #pragma unroll
    for (int pp = 0; pp < 2; ++pp)
      #pragma unroll
      for (int c = 0; c < 8; ++c){
        mv[pp].x = fminf(mv[pp].x, fabsf(acc[pp][c].x));
        mv[pp].y = fminf(mv[pp].y, fabsf(acc[pp][c].y));
      }
    #pragma unroll
    for (int offw = 2; offw < 64; offw <<= 1){
      #pragma unroll
      for (int pp = 0; pp < 2; ++pp){
        mv[pp].x = fminf(mv[pp].x, __shfl_xor(mv[pp].x, offw));
        mv[pp].y = fminf(mv[pp].y, __shfl_xor(mv[pp].y, offw));
      }
    }
    if ((threadIdx.x & 63) < 2){
      #pragma unroll
      for (int pp = 0; pp < 2; ++pp){
        atomicMin(mn + maps + bl*8 + 4*og + 2*pp,     __float_as_uint(mv[pp].x));
        atomicMin(mn + maps + bl*8 + 4*og + 2*pp + 1, __float_as_uint(mv[pp].y));
      }
    }
    #pragma unroll
    for (int pp = 0; pp < 2; ++pp){
      #pragma unroll
      for (int oo = 0; oo < 2; ++oo){
        const int o = 4*og + 2*pp + oo;
        size_t base = (size_t)(bl*8+o)*HWo + (size_t)y*Ho + xbase;
        ushort4 h4a = make_ushort4(
          f2b(oo ? acc[pp][0].y : acc[pp][0].x),
          f2b(oo ? acc[pp][1].y : acc[pp][1].x),
          f2b(oo ? acc[pp][2].y : acc[pp][2].x),
          f2b(oo ? acc[pp][3].y : acc[pp][3].x));
        *(ushort4*)(T + base) = h4a;
        ushort4 h4b = make_ushort4(
          f2b(oo ? acc[pp][4].y : acc[pp][4].x),
          f2b(oo ? acc[pp][5].y : acc[pp][5].x),
          f2b(oo ? acc[pp][6].y : acc[pp][6].x),
          f2b(oo ? acc[pp][7].y : acc[pp][7].x));
        *(ushort4*)(T + base + 4) = h4b;
      }
    }
    return;
  }

  {
    // --- convr: 3x3 (pad 1), FOUR phases of 2 ch. Thread shard: og=tid&1
    //     (channel quad o=4og+0..3), hh=(tid>>1)&3 (8-col octet),
    //     ty=tid>>3 (row). Each thread 4ch x 8col x 1row (acc[2][8] v2f).
    //     Weights PER-LANE (+4og+2pp); tile 5x float2. Per-accumulator
    //     q-order (0,1,2) preserved (bit-exact). Staged global->LDS in
    //     two 5-reg batches per phase. ---
    float* tile = smem;                       // 2*34*36 = 2448
    float* wlds = smem + 2448;                // 576 floats
    const int idx = bid - g2;
    const int tiles = tprR*tprR;
    const int bl = idx / tiles;
    const int t  = idx - bl*tiles;
    const int Y0 = (t/tprR)*32, X0 = (t - (t/tprR)*tprR)*32;
    const int bg = b0 + bl;
    const float* wb = wr + (size_t)(s*64+bg)*576;
    const float* bb = br + (s*64+bg)*8;
    const int HW = H*H;
    const float* xb = X + (size_t)bl*8*HW;
    const int og = threadIdx.x & 1;           // channel quad (o = 4og+0..3)
    const int hh = (threadIdx.x >> 1) & 3;    // 8-col octet
    const int ty = threadIdx.x >> 3;          // row
    const bool act = (Y0+ty < H) && (X0+8*hh < H);  // only false when H==16
    // stage weights into LDS (576 floats)
    #pragma unroll
    for (int k = 0; k < 3; ++k){
      int e = threadIdx.x + k*BLK;
      if (e < 576) wlds[e] = wb[e];
    }
    v2f acc[2][8];                            // [o-pair pp][local col]
    #pragma unroll
    for (int pp = 0; pp < 2; ++pp){
      v2f b2; b2.x = bb[4*og + 2*pp]; b2.y = bb[4*og + 2*pp + 1];
      #pragma unroll
      for (int c = 0; c < 8; ++c) acc[pp][c] = b2;
    }
    #pragma unroll 1
    for (int ph = 0; ph < 4; ++ph){
      if (ph > 0) __syncthreads();
      #pragma unroll 1
      for (int hb = 0; hb < 2; ++hb){
        float vb[5];
        #pragma unroll
        for (int k = 0; k < 5; ++k){
          int e = threadIdx.x + (hb*5 + k)*BLK;
          float v = 0.f;
          if (e < 2448){
            int cc = e % 36; int rr = (e/36) % 34; int c2 = e/(36*34);
            int gy = Y0 - 1 + rr, gx = X0 - 1 + cc;
            if (cc < 34 && (unsigned)gy < (unsigned)H && (unsigned)gx < (unsigned)H)
              v = xb[(size_t)(ph*2 + c2)*HW + gy*H + gx];
          }
          vb[k] = v;
        }
        #pragma unroll
        for (int k = 0; k < 5; ++k){
          int e = threadIdx.x + (hb*5 + k)*BLK;
          if (e < 2448) tile[e] = vb[k];
        }
      }
      __syncthreads();                        // also covers weight staging
      #pragma unroll 1
      for (int i = 0; i < 2; ++i){
        const float* tch = tile + i*1224;
        const int ig = ph*2 + i;
        #pragma unroll
        for (int p = 0; p < 3; ++p){
          const float* rowp = tch + (ty+p)*36 + 8*hh;
          float e[10];
          #pragma unroll
          for (int j = 0; j < 5; ++j){
            float2 pv = *(const float2*)(rowp + 2*j);
            e[2*j] = pv.x; e[2*j+1] = pv.y;
          }
          const float* wq = wlds + (ig*3+p)*24 + 4*og;   // [q][o], per-lane
          #pragma unroll
          for (int q = 0; q < 3; ++q){
            #pragma unroll
            for (int pp = 0; pp < 2; ++pp){
              v2f W = *(const v2f*)(wq + q*8 + 2*pp);
              #pragma unroll
              for (int c = 0; c < 8; ++c)
                acc[pp][c] += W * e[c + q];
            }
          }
        }
      }
    }
    // epilogue: outputs at row Y0+ty, cols X0+8*hh+c, channels 4og+2pp+oo
    v2f mv[2];
    mv[0].x = FINF; mv[0].y = FINF; mv[1].x = FINF; mv[1].y = FINF;
    if (act){
      #pragma unroll
      for (int pp = 0; pp < 2; ++pp)
        #pragma unroll
        for (int c = 0; c < 8; ++c){
          mv[pp].x = fminf(mv[pp].x, fabsf(acc[pp][c].x));
          mv[pp].y = fminf(mv[pp].y, fabsf(acc[pp][c].y));
        }
    }
    #pragma unroll
    for (int offw = 2; offw < 64; offw <<= 1){
      #pragma unroll
      for (int pp = 0; pp < 2; ++pp){
        mv[pp].x = fminf(mv[pp].x, __shfl_xor(mv[pp].x, offw));
        mv[pp].y = fminf(mv[pp].y, __shfl_xor(mv[pp].y, offw));
      }
    }
    if ((threadIdx.x & 63) < 2){
      #pragma unroll
      for (int pp = 0; pp < 2; ++pp){
        atomicMin(mn + bl*8 + 4*og + 2*pp,     __float_as_uint(mv[pp].x));
        atomicMin(mn + bl*8 + 4*og + 2*pp + 1, __float_as_uint(mv[pp].y));
      }
    }
    if (act){
      #pragma unroll
      for (int pp = 0; pp < 2; ++pp){
        #pragma unroll
        for (int oo = 0; oo < 2; ++oo){
          const int o = 4*og + 2*pp + oo;
          size_t base = (size_t)(bl*8+o)*HW + (size_t)(Y0+ty)*H + X0 + 8*hh;
          ushort4 h4a = make_ushort4(
            f2b(oo ? acc[pp][0].y : acc[pp][0].x),
            f2b(oo ? acc[pp][1].y : acc[pp][1].x),
            f2b(oo ? acc[pp][2].y : acc[pp][2].x),
            f2b(oo ? acc[pp][3].y : acc[pp][3].x));
          *(ushort4*)(D + base) = h4a;
          ushort4 h4b = make_ushort4(
            f2b(oo ? acc[pp][4].y : acc[pp][4].x),
            f2b(oo ? acc[pp][5].y : acc[pp][5].x),
            f2b(oo ? acc[pp][6].y : acc[pp][6].x),
            f2b(oo ? acc[pp][7].y : acc[pp][7].x));
          *(ushort4*)(D + base + 4) = h4b;
        }
      }
    }
  }
}

// s<3: next_x = (dln(Dr)[nearest-up] + dln(Dt)) * dln(Dm), into X. Quarter-px threads.
__global__ void combine_kernel(const unsigned short* __restrict__ dr,
                               const unsigned short* __restrict__ dt,
                               const unsigned short* __restrict__ dm,
                               const unsigned* __restrict__ mn, int maps,
                               float* __restrict__ outx, int H, int total){
  int Ho = 2*H, HWo = Ho*Ho, HW = H*H;
  for (int e = blockIdx.x*blockDim.x + threadIdx.x; e < total; e += gridDim.x*blockDim.x){
    int m = e / HW;
    int qpx = e - m*HW;
    int qy = qpx / H, qx = qpx - qy*H;
    float mr = __uint_as_float(mn[m]);
    float mt = __uint_as_float(mn[maps + m]);
    float mm = __uint_as_float(mn[2*maps + m]);
    float r = dln_one(b2f(dr[(size_t)m*HW + qpx]), mr);
    #pragma unroll
    for (int dy = 0; dy < 2; ++dy){
      size_t base = (size_t)m*HWo + (2*qy+dy)*Ho + 2*qx;
      ushort2 tv = *(const ushort2*)(dt + base);
      ushort2 mv = *(const ushort2*)(dm + base);
      float2 ov;
      ov.x = (r + dln_one(b2f(tv.x), mt)) * dln_one(b2f(mv.x), mm);
      ov.y = (r + dln_one(b2f(tv.y), mt)) * dln_one(b2f(mv.y), mm);
      *(float2*)(outx + base) = ov;
    }
  }
}

// s==3: combine + final dynamic 1x1 conv (8->3 ch) fused, writes d_out.
__global__ void combineF_kernel(const unsigned short* __restrict__ dr,
                                const unsigned short* __restrict__ dt,
                                const unsigned short* __restrict__ dm,
                                const unsigned* __restrict__ mn, int maps,
                                const float* __restrict__ wo, const float* __restrict__ bo,
                                float* __restrict__ out, int b0, int total){
  for (int e = blockIdx.x*blockDim.x + threadIdx.x; e < total; e += gridDim.x*blockDim.x){
    int bl = e >> 14;
    int qpx = e & 16383;
    int qy = qpx >> 7, qx = qpx & 127;
    int bg = b0 + bl;
    float r[8], mtv[8], mmv[8];
    #pragma unroll
    for (int o = 0; o < 8; ++o){
      int m = bl*8 + o;
      float mr = __uint_as_float(mn[m]);
      mtv[o] = __uint_as_float(mn[maps + m]);
      mmv[o] = __uint_as_float(mn[2*maps + m]);
      r[o] = dln_one(b2f(dr[(size_t)m*16384 + qpx]), mr);
    }
    #pragma unroll
    for (int dy = 0; dy < 2; ++dy){
      int y = 2*qy + dy, xx = 2*qx;
      float2 acc[3];
      #pragma unroll
      for (int of = 0; of < 3; ++of){
        float b = bo[bg*3 + of];
        acc[of].x = b; acc[of].y = b;
      }
      #pragma unroll
      for (int o = 0; o < 8; ++o){
        size_t base = (size_t)(bl*8+o)*65536 + y*256 + xx;
        ushort2 tv = *(const ushort2*)(dt + base);
        ushort2 mv = *(const ushort2*)(dm + base);
        float vx = (r[o] + dln_one(b2f(tv.x), mtv[o])) * dln_one(b2f(mv.x), mmv[o]);
        float vy = (r[o] + dln_one(b2f(tv.y), mtv[o])) * dln_one(b2f(mv.y), mmv[o]);
        #pragma unroll
        for (int of = 0; of < 3; ++of){
          float w = wo[bg*24 + of*8 + o];
          acc[of].x += w*vx; acc[of].y += w*vy;
        }
      }
      #pragma unroll
      for (int of = 0; of < 3; ++of){
        *(float2*)(out + ((size_t)(bg*3 + of))*65536 + y*256 + xx) = acc[of];
      }
    }
  }
}

static inline int grid_for(long long total){
  long long g = (total + BLK - 1) / BLK;
  if (g > 16384) g = 16384;
  if (g < 1) g = 1;
  return (int)g;
}

extern "C" void kernel_launch(void* const* d_in, const int* in_sizes, int n_in,
                              void* d_out, int out_size, void* d_ws, size_t ws_size,
                              hipStream_t stream){
  (void)in_sizes; (void)n_in; (void)out_size;
  const int*   ids   = (const int*)d_in[0];
  const float* cache = (const float*)d_in[1];
  const float* lat   = (const float*)d_in[2];
  const float* Wr = (const float*)d_in[3];
  const float* Ur = (const float*)d_in[4];
  const float* Vr = (const float*)d_in[5];
  const float* Br = (const float*)d_in[6];
  const float* Wt = (const float*)d_in[7];
  const float* Ut = (const float*)d_in[8];
  const float* Vt = (const float*)d_in[9];
  const float* Bt = (const float*)d_in[10];
  const float* Wm = (const float*)d_in[11];
  const float* Um = (const float*)d_in[12];
  const float* Vm = (const float*)d_in[13];
  const float* Bm = (const float*)d_in[14];
  const float* Wo = (const float*)d_in[15];
  const float* Uo = (const float*)d_in[16];
  const float* Vo = (const float*)d_in[17];
  const float* Bo = (const float*)d_in[18];
  float* out = (float*)d_out;
  float* ws  = (float*)d_ws;

  size_t off = 0;
  auto alloc = [&](size_t n){ size_t o = off; off += n; return o; };
  size_t o_ctx = alloc(2048);
  size_t o_ur = alloc(4*64*128),  o_vr = alloc(4*64*1152);
  size_t o_ut = alloc(4*64*128),  o_vt = alloc(4*64*2048);
  size_t o_um = alloc(4*64*128),  o_vm = alloc(4*64*3200);
  size_t o_br = alloc(4*64*8), o_bt = alloc(4*64*8), o_bm = alloc(4*64*8);
  size_t o_uo = alloc(64*48), o_vo = alloc(64*128), o_bo = alloc(64*3);
  size_t o_wr = alloc(4*64*8*72), o_wt = alloc(4*64*8*128), o_wm = alloc(4*64*8*200);
  size_t o_wo = alloc(64*24);
  size_t o_w2 = alloc((size_t)4*64*4096);   // combined convm weights
  size_t o_mn = alloc(4*3*512);             // [stage][3][maps]
  size_t small_end = off;

  // per sample (float units): X 131072 + D 65536 (bf16) + T 262144 + M 262144
  const size_t perS = 131072 + 65536 + 262144 + 262144;
  size_t ws_f = ws_size / sizeof(float);
  int nb = 64;
  while (nb > 1 && small_end + (size_t)nb*perS > ws_f) nb >>= 1;

  size_t o_X = small_end;
  size_t o_D = o_X + (size_t)nb*131072;
  size_t o_T = o_D + (size_t)nb*65536;
  size_t o_M = o_T + (size_t)nb*262144;
  unsigned* mn = (unsigned*)(ws + o_mn);
  unsigned short* Db = (unsigned short*)(ws + o_D);
  unsigned short* Tb = (unsigned short*)(ws + o_T);
  unsigned short* Mb = (unsigned short*)(ws + o_M);

  gather_ctx_kernel<<<8, BLK, 0, stream>>>(ids, cache, ws + o_ctx);

  W1Args a1;
  a1.M[0]=Ur;  a1.out[0]=ws+o_ur;
  a1.M[1]=Vr;  a1.out[1]=ws+o_vr;
  a1.M[2]=Ut;  a1.out[2]=ws+o_ut;
  a1.M[3]=Vt;  a1.out[3]=ws+o_vt;
  a1.M[4]=Um;  a1.out[4]=ws+o_um;
  a1.M[5]=Vm;  a1.out[5]=ws+o_vm;
  a1.M[6]=Br;  a1.out[6]=ws+o_br;
  a1.M[7]=Bt;  a1.out[7]=ws+o_bt;
  a1.M[8]=Bm;  a1.out[8]=ws+o_bm;
  a1.M[9]=Uo;  a1.out[9]=ws+o_uo;
  a1.M[10]=Vo; a1.out[10]=ws+o_vo;
  a1.M[11]=Bo; a1.out[11]=ws+o_bo;
  w1_kernel<<<256, BLK, 0, stream>>>(ws + o_ctx, a1);

  W2Args a2;
  a2.W[0]=Wr; a2.u[0]=ws+o_ur; a2.v[0]=ws+o_vr; a2.out[0]=ws+o_wr;
  a2.W[1]=Wt; a2.u[1]=ws+o_ut; a2.v[1]=ws+o_vt; a2.out[1]=ws+o_wt;
  a2.W[2]=Wm; a2.u[2]=ws+o_um; a2.v[2]=ws+o_vm; a2.out[2]=ws+o_wm;
  a2.W[3]=Wo; a2.u[3]=ws+o_uo; a2.v[3]=ws+o_vo; a2.out[3]=ws+o_wo;
  w2_kernel<<<256, BLK, 0, stream>>>(a2);

  w4_kernel<<<64, BLK, 0, stream>>>(ws + o_wm, ws + o_w2);

  for (int b0 = 0; b0 < 64; b0 += nb){
    gather_x_kernel<<<grid_for((long long)nb*2048), BLK, 0, stream>>>(
        ids, lat, ws+o_X, b0, nb);
    int maps = nb*8;
    init_min_kernel<<<(4*3*maps + BLK-1)/BLK, BLK, 0, stream>>>(mn, 4*3*maps);
    int H = 16;
    for (int s = 0; s < 4; ++s){
      int Ho = 2*H;
      int tprR = (H >= 32) ? H/32 : 1;
      int tprO = Ho/32;
      int gR = nb*tprR*tprR;
      int gT = nb*tprO*tprO;
      int gM = nb*tprO*tprO;
      int gSN = 8*nb;                          // strips first (1 px/thread)
      int g1 = gSN + gM, g2 = g1 + gT;         // then convm, convt, convr
      unsigned* mns = mn + (size_t)s*3*maps;
      conv3_fused<<<g2 + gR, BLK, 0, stream>>>(
          ws+o_X, ws+o_wr, ws+o_br, ws+o_wt, ws+o_bt, ws+o_wm, ws+o_bm,
          ws+o_w2, Db, Tb, Mb, mns, maps, H, b0, s, tprR, tprO, gSN, g1, g2);
      if (s < 3){
        long long totalq = (long long)maps*H*H;
        combine_kernel<<<grid_for(totalq), BLK, 0, stream>>>(
            Db, Tb, Mb, mns, maps, ws+o_X, H, (int)totalq);
      } else {
        long long totalf = (long long)nb*16384;
        combineF_kernel<<<grid_for(totalf), BLK, 0, stream>>>(
            Db, Tb, Mb, mns, maps, ws+o_wo, ws+o_bo, out, b0, (int)totalf);
      }
      H = Ho;
    }
  }
}